// Round 1
// baseline (498.210 us; speedup 1.0000x reference)
//
#include <hip/hip_runtime.h>

#define NSRC1 292864
#define NDST1 11264
#define NE1   281600
#define NDST2 1024
#define NE2   10240
// IN = H = 256, C = 47

// ---------------------------------------------------------------------------
// Segmented mean aggregation over sorted dst. One block per destination row.
// 64 threads, each owns 4 contiguous columns (float4): one wave reads a full
// 1KB source row per iteration, fully coalesced.
// ---------------------------------------------------------------------------
__global__ __launch_bounds__(64) void agg_kernel(
    const float* __restrict__ feat,      // [n_src, 256]
    const int*   __restrict__ src_idx,   // [n_edges]
    const int*   __restrict__ dst_idx,   // [n_edges] sorted ascending
    int n_edges,
    float* __restrict__ out)             // [gridDim.x, 256] mean-aggregated
{
    const int d = blockIdx.x;

    // lower_bound(dst_idx, d)
    int lo = 0, hi = n_edges;
    while (lo < hi) { int mid = (lo + hi) >> 1; if (dst_idx[mid] <  d) lo = mid + 1; else hi = mid; }
    const int start = lo;
    // upper_bound(dst_idx, d)
    hi = n_edges;
    while (lo < hi) { int mid = (lo + hi) >> 1; if (dst_idx[mid] <= d) lo = mid + 1; else hi = mid; }
    const int end = lo;

    const int c4 = threadIdx.x;   // float4 column index, 0..63
    float4 acc = make_float4(0.f, 0.f, 0.f, 0.f);
    for (int e = start; e < end; ++e) {
        const int s = src_idx[e];
        const float4 v = ((const float4*)(feat + (size_t)s * 256))[c4];
        acc.x += v.x; acc.y += v.y; acc.z += v.z; acc.w += v.w;
    }
    const int deg = end - start;
    const float inv = 1.0f / (deg > 0 ? (float)deg : 1.0f);
    acc.x *= inv; acc.y *= inv; acc.z *= inv; acc.w *= inv;
    ((float4*)(out + (size_t)d * 256))[c4] = acc;
}

// ---------------------------------------------------------------------------
// Layer-1 fused GEMM: h = relu(x_dst @ Ws + hn @ Wn + b)
// M=11264, N=256, K=256 per phase (2 phases). fp32 VALU, 64x64 block tile,
// BK=16, 256 threads, 4x4 accumulators per thread.
// ---------------------------------------------------------------------------
__global__ __launch_bounds__(256) void gemm1_kernel(
    const float* __restrict__ x,    // [>=11264, 256]  (h_dst rows)
    const float* __restrict__ hn,   // [11264, 256]
    const float* __restrict__ Ws,   // [256, 256]
    const float* __restrict__ Wn,   // [256, 256]
    const float* __restrict__ b,    // [256]
    float* __restrict__ h)          // [11264, 256]
{
    __shared__ float As[64][17];    // +1 pad: conflict-free column reads
    __shared__ float Bs[16][64];

    const int tid = threadIdx.x;
    const int tx = tid & 15, ty = tid >> 4;
    const int mblk = blockIdx.x * 64, nblk = blockIdx.y * 64;

    float acc[4][4] = {};

    const float* Aptr[2] = { x, hn };
    const float* Bptr[2] = { Ws, Wn };

    for (int phase = 0; phase < 2; ++phase) {
        const float* __restrict__ A = Aptr[phase];
        const float* __restrict__ B = Bptr[phase];
        for (int kt = 0; kt < 256; kt += 16) {
            // A tile load: 64 rows x 16 k. One float4 per thread.
            {
                const int ar = tid >> 2, ak = (tid & 3) << 2;
                const float4 av = *(const float4*)(A + (size_t)(mblk + ar) * 256 + kt + ak);
                As[ar][ak + 0] = av.x; As[ar][ak + 1] = av.y;
                As[ar][ak + 2] = av.z; As[ar][ak + 3] = av.w;
            }
            // B tile load: 16 k x 64 n. One float4 per thread.
            {
                const int br = tid >> 4, bn = (tid & 15) << 2;
                const float4 bv = *(const float4*)(B + (size_t)(kt + br) * 256 + nblk + bn);
                *(float4*)&Bs[br][bn] = bv;
            }
            __syncthreads();
            #pragma unroll
            for (int kk = 0; kk < 16; ++kk) {
                float a0 = As[ty * 4 + 0][kk];
                float a1 = As[ty * 4 + 1][kk];
                float a2 = As[ty * 4 + 2][kk];
                float a3 = As[ty * 4 + 3][kk];
                float b0 = Bs[kk][tx * 4 + 0];
                float b1 = Bs[kk][tx * 4 + 1];
                float b2 = Bs[kk][tx * 4 + 2];
                float b3 = Bs[kk][tx * 4 + 3];
                acc[0][0] += a0 * b0; acc[0][1] += a0 * b1; acc[0][2] += a0 * b2; acc[0][3] += a0 * b3;
                acc[1][0] += a1 * b0; acc[1][1] += a1 * b1; acc[1][2] += a1 * b2; acc[1][3] += a1 * b3;
                acc[2][0] += a2 * b0; acc[2][1] += a2 * b1; acc[2][2] += a2 * b2; acc[2][3] += a2 * b3;
                acc[3][0] += a3 * b0; acc[3][1] += a3 * b1; acc[3][2] += a3 * b2; acc[3][3] += a3 * b3;
            }
            __syncthreads();
        }
    }

    #pragma unroll
    for (int i = 0; i < 4; ++i) {
        const int m = mblk + ty * 4 + i;
        #pragma unroll
        for (int j = 0; j < 4; ++j) {
            const int n = nblk + tx * 4 + j;
            float v = acc[i][j] + b[n];
            h[(size_t)m * 256 + n] = v > 0.f ? v : 0.f;
        }
    }
}

// ---------------------------------------------------------------------------
// Layer-2 output GEMM: out = h_dst @ Ws2 + hn2 @ Wn2 + b2
// M=1024, C=47, K=256(x2). One block per output row, lane = output column.
// ---------------------------------------------------------------------------
__global__ __launch_bounds__(64) void out_kernel(
    const float* __restrict__ h,    // [>=1024, 256]
    const float* __restrict__ hn2,  // [1024, 256]
    const float* __restrict__ Ws,   // [256, 47]
    const float* __restrict__ Wn,   // [256, 47]
    const float* __restrict__ b,    // [47]
    float* __restrict__ out)        // [1024, 47]
{
    const int m = blockIdx.x;
    const int c = threadIdx.x;
    if (c >= 47) return;
    float acc = b[c];
    const float* __restrict__ hrow  = h   + (size_t)m * 256;
    const float* __restrict__ hnrow = hn2 + (size_t)m * 256;
    for (int k = 0; k < 256; ++k) {
        acc += hrow[k] * Ws[k * 47 + c] + hnrow[k] * Wn[k * 47 + c];
    }
    out[(size_t)m * 47 + c] = acc;
}

extern "C" void kernel_launch(void* const* d_in, const int* in_sizes, int n_in,
                              void* d_out, int out_size, void* d_ws, size_t ws_size,
                              hipStream_t stream) {
    const float* x    = (const float*)d_in[0];
    const int*   src1 = (const int*)  d_in[1];
    const int*   dst1 = (const int*)  d_in[2];
    const int*   src2 = (const int*)  d_in[3];
    const int*   dst2 = (const int*)  d_in[4];
    const float* Ws1  = (const float*)d_in[5];
    const float* Wn1  = (const float*)d_in[6];
    const float* b1   = (const float*)d_in[7];
    const float* Ws2  = (const float*)d_in[8];
    const float* Wn2  = (const float*)d_in[9];
    const float* b2   = (const float*)d_in[10];
    float* out = (float*)d_out;

    char* ws = (char*)d_ws;
    const size_t sz_h1 = (size_t)NDST1 * 256 * sizeof(float);   // 11.5 MB
    float* hn1 = (float*)(ws);
    float* h   = (float*)(ws + sz_h1);
    float* hn2 = (float*)(ws + 2 * sz_h1);                       // 1 MB

    // Layer 1: neighbor mean
    agg_kernel<<<NDST1, 64, 0, stream>>>(x, src1, dst1, NE1, hn1);
    // Layer 1: fused dual GEMM + bias + relu
    dim3 g1(NDST1 / 64, 256 / 64);
    gemm1_kernel<<<g1, 256, 0, stream>>>(x, hn1, Ws1, Wn1, b1, h);
    // Layer 2: neighbor mean over h
    agg_kernel<<<NDST2, 64, 0, stream>>>(h, src2, dst2, NE2, hn2);
    // Layer 2: output GEMM
    out_kernel<<<NDST2, 64, 0, stream>>>(h, hn2, Ws2, Wn2, b2, out);
}

// Round 2
// 483.409 us; speedup vs baseline: 1.0306x; 1.0306x over previous
//
#include <hip/hip_runtime.h>

#define NSRC1 292864
#define NDST1 11264
#define NE1   281600
#define NDST2 1024
#define NE2   10240
// IN = H = 256, C = 47, K_concat = 512

typedef __bf16 bf16x8 __attribute__((ext_vector_type(8)));
typedef float  f32x4  __attribute__((ext_vector_type(4)));

__device__ __forceinline__ unsigned short f2bf(float f) {
    union { float f; unsigned u; } v; v.f = f;
    unsigned r = v.u + 0x7FFF + ((v.u >> 16) & 1);   // RNE
    return (unsigned short)(r >> 16);
}

// ---------------------------------------------------------------------------
// Layer-1 aggregation, fused with bf16 A-matrix build.
// Abf[d][0:256]   = bf16(x[d])            (self features)
// Abf[d][256:512] = bf16(mean_neigh(d))   (aggregated features)
// 4 dsts per 256-thread block (one per wave) for better waves/CU.
// ---------------------------------------------------------------------------
__global__ __launch_bounds__(256) void agg1_fused_kernel(
    const float* __restrict__ x,         // [NSRC1, 256]
    const int*   __restrict__ src_idx,   // [NE1]
    const int*   __restrict__ dst_idx,   // [NE1] sorted
    unsigned short* __restrict__ Abf)    // [NDST1, 512] bf16 bits
{
    const int lane = threadIdx.x & 63;
    const int w    = threadIdx.x >> 6;
    const int d    = blockIdx.x * 4 + w;

    // lower_bound / upper_bound on sorted dst_idx
    int lo = 0, hi = NE1;
    while (lo < hi) { int mid = (lo + hi) >> 1; if (dst_idx[mid] <  d) lo = mid + 1; else hi = mid; }
    const int start = lo;
    hi = NE1;
    while (lo < hi) { int mid = (lo + hi) >> 1; if (dst_idx[mid] <= d) lo = mid + 1; else hi = mid; }
    const int end = lo;

    float4 acc = make_float4(0.f, 0.f, 0.f, 0.f);
    for (int e = start; e < end; ++e) {
        const int s = src_idx[e];
        const float4 v = ((const float4*)(x + (size_t)s * 256))[lane];
        acc.x += v.x; acc.y += v.y; acc.z += v.z; acc.w += v.w;
    }
    const int deg = end - start;
    const float inv = 1.0f / (deg > 0 ? (float)deg : 1.0f);

    // neighbor half (cols 256..511)
    ushort4 nb;
    nb.x = f2bf(acc.x * inv); nb.y = f2bf(acc.y * inv);
    nb.z = f2bf(acc.z * inv); nb.w = f2bf(acc.w * inv);
    *(ushort4*)(Abf + (size_t)d * 512 + 256 + lane * 4) = nb;

    // self half (cols 0..255)
    const float4 xv = ((const float4*)(x + (size_t)d * 256))[lane];
    ushort4 sf;
    sf.x = f2bf(xv.x); sf.y = f2bf(xv.y); sf.z = f2bf(xv.z); sf.w = f2bf(xv.w);
    *(ushort4*)(Abf + (size_t)d * 512 + lane * 4) = sf;
}

// ---------------------------------------------------------------------------
// Weight prep: Wt[n][k] = bf16( k<256 ? Ws1[k][n] : Wn1[k-256][n] )
// n-major so B fragments are contiguous in k. LDS transpose, coalesced I/O.
// grid (8, 4): 64x64 tiles of the [512 k, 256 n] space.
// ---------------------------------------------------------------------------
__global__ __launch_bounds__(256) void prep_wt_kernel(
    const float* __restrict__ Ws, const float* __restrict__ Wn,
    unsigned short* __restrict__ Wt)     // [256, 512] bf16 bits
{
    __shared__ float t[64][65];
    const int kb = blockIdx.x * 64, nb = blockIdx.y * 64;
    const float* __restrict__ W = (kb < 256) ? Ws : Wn;
    const int kofs = (kb < 256) ? kb : kb - 256;
    const int c  = threadIdx.x & 63;
    const int r0 = threadIdx.x >> 6;
    #pragma unroll
    for (int i = 0; i < 16; ++i) {
        const int r = r0 + i * 4;
        t[r][c] = W[(size_t)(kofs + r) * 256 + nb + c];   // coalesced over c
    }
    __syncthreads();
    #pragma unroll
    for (int i = 0; i < 16; ++i) {
        const int r = r0 + i * 4;  // r = n-within-tile, c = k-within-tile
        Wt[(size_t)(nb + r) * 512 + kb + c] = f2bf(t[c][r]);  // coalesced over c
    }
}

// ---------------------------------------------------------------------------
// Layer-1 GEMM on MFMA: h = relu(Abf @ Wt^T + b), fp32 out.
// M=11264, N=256, K=512. BM=128, BN=64, BK=32; 4 waves, each 64x32.
// 16x16x32 bf16 MFMA; A/B frags: row/col = lane&15, k0 = (lane>>4)*8;
// D: col = lane&15, row = (lane>>4)*4 + reg.
// ---------------------------------------------------------------------------
#define LDT 40   // LDS k-stride (bf16 elems): 80B rows, 16B-aligned, spreads banks

__global__ __launch_bounds__(256) void gemm1_mfma_kernel(
    const unsigned short* __restrict__ Abf,   // [NDST1, 512]
    const unsigned short* __restrict__ Wt,    // [256, 512]
    const float* __restrict__ bias,           // [256]
    float* __restrict__ h)                    // [NDST1, 256]
{
    __shared__ unsigned short As[128][LDT];   // 10 KB
    __shared__ unsigned short Bs[64][LDT];    // 5 KB

    const int tid  = threadIdx.x;
    const int lane = tid & 63;
    const int w    = tid >> 6;
    const int wm   = (w & 1) * 64;
    const int wn   = (w >> 1) * 32;
    const int mblk = blockIdx.x * 128;
    const int nblk = blockIdx.y * 64;

    const int r16 = lane & 15;
    const int k0  = (lane >> 4) * 8;

    f32x4 acc[4][2] = {};

    for (int kt = 0; kt < 512; kt += 32) {
        // A tile: 128 rows x 32 k = 512 16B-chunks, 2 per thread
        #pragma unroll
        for (int i = 0; i < 2; ++i) {
            const int idx = tid + i * 256;
            const int r  = idx >> 2;
            const int kk = (idx & 3) * 8;
            *(uint4*)&As[r][kk] =
                *(const uint4*)(Abf + (size_t)(mblk + r) * 512 + kt + kk);
        }
        // B tile: 64 rows x 32 k = 256 16B-chunks, 1 per thread
        {
            const int r  = tid >> 2;
            const int kk = (tid & 3) * 8;
            *(uint4*)&Bs[r][kk] =
                *(const uint4*)(Wt + (size_t)(nblk + r) * 512 + kt + kk);
        }
        __syncthreads();

        bf16x8 bfrag[2];
        #pragma unroll
        for (int ni = 0; ni < 2; ++ni)
            bfrag[ni] = *(const bf16x8*)&Bs[wn + ni * 16 + r16][k0];
        #pragma unroll
        for (int mi = 0; mi < 4; ++mi) {
            const bf16x8 afrag = *(const bf16x8*)&As[wm + mi * 16 + r16][k0];
            #pragma unroll
            for (int ni = 0; ni < 2; ++ni)
                acc[mi][ni] = __builtin_amdgcn_mfma_f32_16x16x32_bf16(
                    afrag, bfrag[ni], acc[mi][ni], 0, 0, 0);
        }
        __syncthreads();
    }

    #pragma unroll
    for (int mi = 0; mi < 4; ++mi) {
        #pragma unroll
        for (int ni = 0; ni < 2; ++ni) {
            const int col = nblk + wn + ni * 16 + r16;
            const float bb = bias[col];
            #pragma unroll
            for (int r = 0; r < 4; ++r) {
                const int row = mblk + wm + mi * 16 + (lane >> 4) * 4 + r;
                const float v = acc[mi][ni][r] + bb;
                h[(size_t)row * 256 + col] = v > 0.f ? v : 0.f;
            }
        }
    }
}

// ---------------------------------------------------------------------------
// Layer-2 aggregation (fp32, tiny): one dst per 64-thread block.
// ---------------------------------------------------------------------------
__global__ __launch_bounds__(64) void agg2_kernel(
    const float* __restrict__ feat,      // [NDST1, 256] = h
    const int*   __restrict__ src_idx,   // [NE2]
    const int*   __restrict__ dst_idx,   // [NE2] sorted
    float* __restrict__ out)             // [NDST2, 256]
{
    const int d = blockIdx.x;
    int lo = 0, hi = NE2;
    while (lo < hi) { int mid = (lo + hi) >> 1; if (dst_idx[mid] <  d) lo = mid + 1; else hi = mid; }
    const int start = lo;
    hi = NE2;
    while (lo < hi) { int mid = (lo + hi) >> 1; if (dst_idx[mid] <= d) lo = mid + 1; else hi = mid; }
    const int end = lo;

    const int c4 = threadIdx.x;
    float4 acc = make_float4(0.f, 0.f, 0.f, 0.f);
    for (int e = start; e < end; ++e) {
        const int s = src_idx[e];
        const float4 v = ((const float4*)(feat + (size_t)s * 256))[c4];
        acc.x += v.x; acc.y += v.y; acc.z += v.z; acc.w += v.w;
    }
    const int deg = end - start;
    const float inv = 1.0f / (deg > 0 ? (float)deg : 1.0f);
    acc.x *= inv; acc.y *= inv; acc.z *= inv; acc.w *= inv;
    ((float4*)(out + (size_t)d * 256))[c4] = acc;
}

// ---------------------------------------------------------------------------
// Layer-2 output GEMM (fp32 VALU, tiny): out = h_dst @ Ws2 + hn2 @ Wn2 + b2
// ---------------------------------------------------------------------------
__global__ __launch_bounds__(64) void out_kernel(
    const float* __restrict__ h,    // [NDST1, 256]
    const float* __restrict__ hn2,  // [NDST2, 256]
    const float* __restrict__ Ws,   // [256, 47]
    const float* __restrict__ Wn,   // [256, 47]
    const float* __restrict__ b,    // [47]
    float* __restrict__ out)        // [NDST2, 47]
{
    const int m = blockIdx.x;
    const int c = threadIdx.x;
    if (c >= 47) return;
    float acc = b[c];
    const float* __restrict__ hrow  = h   + (size_t)m * 256;
    const float* __restrict__ hnrow = hn2 + (size_t)m * 256;
    for (int k = 0; k < 256; ++k) {
        acc += hrow[k] * Ws[k * 47 + c] + hnrow[k] * Wn[k * 47 + c];
    }
    out[(size_t)m * 47 + c] = acc;
}

extern "C" void kernel_launch(void* const* d_in, const int* in_sizes, int n_in,
                              void* d_out, int out_size, void* d_ws, size_t ws_size,
                              hipStream_t stream) {
    const float* x    = (const float*)d_in[0];
    const int*   src1 = (const int*)  d_in[1];
    const int*   dst1 = (const int*)  d_in[2];
    const int*   src2 = (const int*)  d_in[3];
    const int*   dst2 = (const int*)  d_in[4];
    const float* Ws1  = (const float*)d_in[5];
    const float* Wn1  = (const float*)d_in[6];
    const float* b1   = (const float*)d_in[7];
    const float* Ws2  = (const float*)d_in[8];
    const float* Wn2  = (const float*)d_in[9];
    const float* b2   = (const float*)d_in[10];
    float* out = (float*)d_out;

    char* ws = (char*)d_ws;
    const size_t sz_Abf = (size_t)NDST1 * 512 * sizeof(unsigned short); // 11.5 MB
    const size_t sz_h   = (size_t)NDST1 * 256 * sizeof(float);          // 11.5 MB
    const size_t sz_hn2 = (size_t)NDST2 * 256 * sizeof(float);          // 1 MB
    unsigned short* Abf = (unsigned short*)(ws);
    float*          h   = (float*)(ws + sz_Abf);
    float*          hn2 = (float*)(ws + sz_Abf + sz_h);
    unsigned short* Wt  = (unsigned short*)(ws + sz_Abf + sz_h + sz_hn2);

    // Weight transpose+cast (independent of agg1; tiny)
    dim3 gw(8, 4);
    prep_wt_kernel<<<gw, 256, 0, stream>>>(Ws1, Wn1, Wt);
    // Layer 1 aggregation fused with bf16 A build
    agg1_fused_kernel<<<NDST1 / 4, 256, 0, stream>>>(x, src1, dst1, Abf);
    // Layer 1 MFMA GEMM + bias + relu
    dim3 g1(NDST1 / 128, 256 / 64);
    gemm1_mfma_kernel<<<g1, 256, 0, stream>>>(Abf, Wt, b1, h);
    // Layer 2
    agg2_kernel<<<NDST2, 64, 0, stream>>>(h, src2, dst2, hn2);
    out_kernel<<<NDST2, 64, 0, stream>>>(h, hn2, Ws2, Wn2, b2, out);
}

// Round 3
// 451.919 us; speedup vs baseline: 1.1024x; 1.0697x over previous
//
#include <hip/hip_runtime.h>

#define NSRC1 292864
#define NDST1 11264
#define NE1   281600
#define NDST2 1024
#define NE2   10240
// IN = H = 256, C = 47, K_concat = 512

typedef __bf16 bf16x8 __attribute__((ext_vector_type(8)));
typedef float  f32x4  __attribute__((ext_vector_type(4)));

__device__ __forceinline__ unsigned short f2bf(float f) {
    union { float f; unsigned u; } v; v.f = f;
    unsigned r = v.u + 0x7FFF + ((v.u >> 16) & 1);   // RNE
    return (unsigned short)(r >> 16);
}

// ---------------------------------------------------------------------------
// CSR rowptr build for both graphs: one thread per edge, writes the start
// offset for every dst it "opens". Replaces per-wave binary searches.
// ---------------------------------------------------------------------------
__global__ __launch_bounds__(256) void rowptr_kernel(
    const int* __restrict__ dst1, const int* __restrict__ dst2,
    int* __restrict__ rp1, int* __restrict__ rp2)
{
    const int t = blockIdx.x * 256 + threadIdx.x;
    if (t < NE1) {
        const int d  = dst1[t];
        const int dp = (t == 0) ? -1 : dst1[t - 1];
        for (int j = dp + 1; j <= d; ++j) rp1[j] = t;
        if (t == NE1 - 1) for (int j = d + 1; j <= NDST1; ++j) rp1[j] = NE1;
    } else if (t - NE1 < NE2) {
        const int e  = t - NE1;
        const int d  = dst2[e];
        const int dp = (e == 0) ? -1 : dst2[e - 1];
        for (int j = dp + 1; j <= d; ++j) rp2[j] = e;
        if (e == NE2 - 1) for (int j = d + 1; j <= NDST2; ++j) rp2[j] = NE2;
    }
}

// ---------------------------------------------------------------------------
// Layer-1 aggregation fused with bf16 A-matrix build.
// Abf[d][0:256] = bf16(x[d]); Abf[d][256:512] = bf16(mean_neigh(d)).
// One dst per wave, 4 waves/block. Edge loop unrolled x4 with independent
// accumulators -> 4 row-gathers in flight per wave.
// ---------------------------------------------------------------------------
__global__ __launch_bounds__(256) void agg1_fused_kernel(
    const float* __restrict__ x,         // [NSRC1, 256]
    const int*   __restrict__ src_idx,   // [NE1]
    const int*   __restrict__ rowptr,    // [NDST1+1]
    unsigned short* __restrict__ Abf)    // [NDST1, 512] bf16 bits
{
    const int lane = threadIdx.x & 63;
    const int w    = threadIdx.x >> 6;
    const int d    = blockIdx.x * 4 + w;

    const int start = rowptr[d];
    const int end   = rowptr[d + 1];

    float4 a0 = make_float4(0.f,0.f,0.f,0.f);
    float4 a1 = a0, a2 = a0, a3 = a0;

    int e = start;
    for (; e + 4 <= end; e += 4) {
        const int s0 = src_idx[e + 0];
        const int s1 = src_idx[e + 1];
        const int s2 = src_idx[e + 2];
        const int s3 = src_idx[e + 3];
        const float4 v0 = ((const float4*)(x + (size_t)s0 * 256))[lane];
        const float4 v1 = ((const float4*)(x + (size_t)s1 * 256))[lane];
        const float4 v2 = ((const float4*)(x + (size_t)s2 * 256))[lane];
        const float4 v3 = ((const float4*)(x + (size_t)s3 * 256))[lane];
        a0.x += v0.x; a0.y += v0.y; a0.z += v0.z; a0.w += v0.w;
        a1.x += v1.x; a1.y += v1.y; a1.z += v1.z; a1.w += v1.w;
        a2.x += v2.x; a2.y += v2.y; a2.z += v2.z; a2.w += v2.w;
        a3.x += v3.x; a3.y += v3.y; a3.z += v3.z; a3.w += v3.w;
    }
    for (; e < end; ++e) {
        const int s = src_idx[e];
        const float4 v = ((const float4*)(x + (size_t)s * 256))[lane];
        a0.x += v.x; a0.y += v.y; a0.z += v.z; a0.w += v.w;
    }
    a0.x += a1.x + a2.x + a3.x;
    a0.y += a1.y + a2.y + a3.y;
    a0.z += a1.z + a2.z + a3.z;
    a0.w += a1.w + a2.w + a3.w;

    const int deg = end - start;
    const float inv = 1.0f / (deg > 0 ? (float)deg : 1.0f);

    ushort4 nb;
    nb.x = f2bf(a0.x * inv); nb.y = f2bf(a0.y * inv);
    nb.z = f2bf(a0.z * inv); nb.w = f2bf(a0.w * inv);
    *(ushort4*)(Abf + (size_t)d * 512 + 256 + lane * 4) = nb;

    const float4 xv = ((const float4*)(x + (size_t)d * 256))[lane];
    ushort4 sf;
    sf.x = f2bf(xv.x); sf.y = f2bf(xv.y); sf.z = f2bf(xv.z); sf.w = f2bf(xv.w);
    *(ushort4*)(Abf + (size_t)d * 512 + lane * 4) = sf;
}

// ---------------------------------------------------------------------------
// Weight prep: Wt[n][k] = bf16( k<256 ? Ws1[k][n] : Wn1[k-256][n] ), n-major.
// ---------------------------------------------------------------------------
__global__ __launch_bounds__(256) void prep_wt_kernel(
    const float* __restrict__ Ws, const float* __restrict__ Wn,
    unsigned short* __restrict__ Wt)     // [256, 512] bf16 bits
{
    __shared__ float t[64][65];
    const int kb = blockIdx.x * 64, nb = blockIdx.y * 64;
    const float* __restrict__ W = (kb < 256) ? Ws : Wn;
    const int kofs = (kb < 256) ? kb : kb - 256;
    const int c  = threadIdx.x & 63;
    const int r0 = threadIdx.x >> 6;
    #pragma unroll
    for (int i = 0; i < 16; ++i) {
        const int r = r0 + i * 4;
        t[r][c] = W[(size_t)(kofs + r) * 256 + nb + c];
    }
    __syncthreads();
    #pragma unroll
    for (int i = 0; i < 16; ++i) {
        const int r = r0 + i * 4;
        Wt[(size_t)(nb + r) * 512 + kb + c] = f2bf(t[c][r]);
    }
}

// ---------------------------------------------------------------------------
// Layer-1 GEMM on MFMA: h = relu(Abf @ Wt^T + b), fp32 out.
// M=11264, N=256, K=512. BM=128, BN=64, BK=32; 4 waves, each 64x32.
// ---------------------------------------------------------------------------
#define LDT 40   // LDS k-stride (bf16): 80B rows, 16B aligned, spreads banks

__global__ __launch_bounds__(256) void gemm1_mfma_kernel(
    const unsigned short* __restrict__ Abf,   // [NDST1, 512]
    const unsigned short* __restrict__ Wt,    // [256, 512]
    const float* __restrict__ bias,           // [256]
    float* __restrict__ h)                    // [NDST1, 256]
{
    __shared__ unsigned short As[128][LDT];
    __shared__ unsigned short Bs[64][LDT];

    const int tid  = threadIdx.x;
    const int lane = tid & 63;
    const int w    = tid >> 6;
    const int wm   = (w & 1) * 64;
    const int wn   = (w >> 1) * 32;
    const int mblk = blockIdx.x * 128;
    const int nblk = blockIdx.y * 64;

    const int r16 = lane & 15;
    const int k0  = (lane >> 4) * 8;

    f32x4 acc[4][2] = {};

    for (int kt = 0; kt < 512; kt += 32) {
        #pragma unroll
        for (int i = 0; i < 2; ++i) {
            const int idx = tid + i * 256;
            const int r  = idx >> 2;
            const int kk = (idx & 3) * 8;
            *(uint4*)&As[r][kk] =
                *(const uint4*)(Abf + (size_t)(mblk + r) * 512 + kt + kk);
        }
        {
            const int r  = tid >> 2;
            const int kk = (tid & 3) * 8;
            *(uint4*)&Bs[r][kk] =
                *(const uint4*)(Wt + (size_t)(nblk + r) * 512 + kt + kk);
        }
        __syncthreads();

        bf16x8 bfrag[2];
        #pragma unroll
        for (int ni = 0; ni < 2; ++ni)
            bfrag[ni] = *(const bf16x8*)&Bs[wn + ni * 16 + r16][k0];
        #pragma unroll
        for (int mi = 0; mi < 4; ++mi) {
            const bf16x8 afrag = *(const bf16x8*)&As[wm + mi * 16 + r16][k0];
            #pragma unroll
            for (int ni = 0; ni < 2; ++ni)
                acc[mi][ni] = __builtin_amdgcn_mfma_f32_16x16x32_bf16(
                    afrag, bfrag[ni], acc[mi][ni], 0, 0, 0);
        }
        __syncthreads();
    }

    #pragma unroll
    for (int mi = 0; mi < 4; ++mi) {
        #pragma unroll
        for (int ni = 0; ni < 2; ++ni) {
            const int col = nblk + wn + ni * 16 + r16;
            const float bb = bias[col];
            #pragma unroll
            for (int r = 0; r < 4; ++r) {
                const int row = mblk + wm + mi * 16 + (lane >> 4) * 4 + r;
                const float v = acc[mi][ni][r] + bb;
                h[(size_t)row * 256 + col] = v > 0.f ? v : 0.f;
            }
        }
    }
}

// ---------------------------------------------------------------------------
// Layer-2 aggregation: one dst per wave, 4 waves/block, rowptr + unroll x4.
// ---------------------------------------------------------------------------
__global__ __launch_bounds__(256) void agg2_kernel(
    const float* __restrict__ feat,      // [NDST1, 256] = h
    const int*   __restrict__ src_idx,   // [NE2]
    const int*   __restrict__ rowptr,    // [NDST2+1]
    float* __restrict__ out)             // [NDST2, 256]
{
    const int lane = threadIdx.x & 63;
    const int w    = threadIdx.x >> 6;
    const int d    = blockIdx.x * 4 + w;

    const int start = rowptr[d];
    const int end   = rowptr[d + 1];

    float4 a0 = make_float4(0.f,0.f,0.f,0.f);
    float4 a1 = a0, a2 = a0, a3 = a0;

    int e = start;
    for (; e + 4 <= end; e += 4) {
        const int s0 = src_idx[e + 0];
        const int s1 = src_idx[e + 1];
        const int s2 = src_idx[e + 2];
        const int s3 = src_idx[e + 3];
        const float4 v0 = ((const float4*)(feat + (size_t)s0 * 256))[lane];
        const float4 v1 = ((const float4*)(feat + (size_t)s1 * 256))[lane];
        const float4 v2 = ((const float4*)(feat + (size_t)s2 * 256))[lane];
        const float4 v3 = ((const float4*)(feat + (size_t)s3 * 256))[lane];
        a0.x += v0.x; a0.y += v0.y; a0.z += v0.z; a0.w += v0.w;
        a1.x += v1.x; a1.y += v1.y; a1.z += v1.z; a1.w += v1.w;
        a2.x += v2.x; a2.y += v2.y; a2.z += v2.z; a2.w += v2.w;
        a3.x += v3.x; a3.y += v3.y; a3.z += v3.z; a3.w += v3.w;
    }
    for (; e < end; ++e) {
        const int s = src_idx[e];
        const float4 v = ((const float4*)(feat + (size_t)s * 256))[lane];
        a0.x += v.x; a0.y += v.y; a0.z += v.z; a0.w += v.w;
    }
    a0.x += a1.x + a2.x + a3.x;
    a0.y += a1.y + a2.y + a3.y;
    a0.z += a1.z + a2.z + a3.z;
    a0.w += a1.w + a2.w + a3.w;

    const int deg = end - start;
    const float inv = 1.0f / (deg > 0 ? (float)deg : 1.0f);
    a0.x *= inv; a0.y *= inv; a0.z *= inv; a0.w *= inv;
    ((float4*)(out + (size_t)d * 256))[lane] = a0;
}

// ---------------------------------------------------------------------------
// Layer-2 output GEMM (fp32 VALU, tiny): 4 rows per 256-thread block.
// ---------------------------------------------------------------------------
__global__ __launch_bounds__(256) void out_kernel(
    const float* __restrict__ h,    // [NDST1, 256]
    const float* __restrict__ hn2,  // [NDST2, 256]
    const float* __restrict__ Ws,   // [256, 47]
    const float* __restrict__ Wn,   // [256, 47]
    const float* __restrict__ b,    // [47]
    float* __restrict__ out)        // [NDST2, 47]
{
    const int w = threadIdx.x >> 6;
    const int c = threadIdx.x & 63;
    const int m = blockIdx.x * 4 + w;
    if (c >= 47) return;
    float acc = b[c];
    const float* __restrict__ hrow  = h   + (size_t)m * 256;
    const float* __restrict__ hnrow = hn2 + (size_t)m * 256;
    #pragma unroll 4
    for (int k = 0; k < 256; ++k) {
        acc += hrow[k] * Ws[k * 47 + c] + hnrow[k] * Wn[k * 47 + c];
    }
    out[(size_t)m * 47 + c] = acc;
}

extern "C" void kernel_launch(void* const* d_in, const int* in_sizes, int n_in,
                              void* d_out, int out_size, void* d_ws, size_t ws_size,
                              hipStream_t stream) {
    const float* x    = (const float*)d_in[0];
    const int*   src1 = (const int*)  d_in[1];
    const int*   dst1 = (const int*)  d_in[2];
    const int*   src2 = (const int*)  d_in[3];
    const int*   dst2 = (const int*)  d_in[4];
    const float* Ws1  = (const float*)d_in[5];
    const float* Wn1  = (const float*)d_in[6];
    const float* b1   = (const float*)d_in[7];
    const float* Ws2  = (const float*)d_in[8];
    const float* Wn2  = (const float*)d_in[9];
    const float* b2   = (const float*)d_in[10];
    float* out = (float*)d_out;

    char* ws = (char*)d_ws;
    const size_t sz_Abf = (size_t)NDST1 * 512 * sizeof(unsigned short); // 11.5 MB
    const size_t sz_h   = (size_t)NDST1 * 256 * sizeof(float);          // 11.5 MB
    const size_t sz_hn2 = (size_t)NDST2 * 256 * sizeof(float);          // 1 MB
    const size_t sz_Wt  = (size_t)256 * 512 * sizeof(unsigned short);   // 256 KB
    const size_t sz_rp1 = (size_t)(NDST1 + 2) * sizeof(int);
    unsigned short* Abf = (unsigned short*)(ws);
    float*          h   = (float*)(ws + sz_Abf);
    float*          hn2 = (float*)(ws + sz_Abf + sz_h);
    unsigned short* Wt  = (unsigned short*)(ws + sz_Abf + sz_h + sz_hn2);
    int*            rp1 = (int*)(ws + sz_Abf + sz_h + sz_hn2 + sz_Wt);
    int*            rp2 = (int*)(ws + sz_Abf + sz_h + sz_hn2 + sz_Wt + sz_rp1);

    // CSR rowptr for both graphs + weight transpose (both cheap, independent)
    rowptr_kernel<<<(NE1 + NE2 + 255) / 256, 256, 0, stream>>>(dst1, dst2, rp1, rp2);
    dim3 gw(8, 4);
    prep_wt_kernel<<<gw, 256, 0, stream>>>(Ws1, Wn1, Wt);
    // Layer 1 aggregation fused with bf16 A build
    agg1_fused_kernel<<<NDST1 / 4, 256, 0, stream>>>(x, src1, rp1, Abf);
    // Layer 1 MFMA GEMM + bias + relu
    dim3 g1(NDST1 / 128, 256 / 64);
    gemm1_mfma_kernel<<<g1, 256, 0, stream>>>(Abf, Wt, b1, h);
    // Layer 2
    agg2_kernel<<<NDST2 / 4, 256, 0, stream>>>(h, src2, rp2, hn2);
    out_kernel<<<NDST2 / 4, 256, 0, stream>>>(h, hn2, Ws2, Wn2, b2, out);
}

// Round 4
// 450.182 us; speedup vs baseline: 1.1067x; 1.0039x over previous
//
#include <hip/hip_runtime.h>

#define NSRC1 292864
#define NDST1 11264
#define NE1   281600
#define NDST2 1024
#define NE2   10240
// IN = H = 256, C = 47, K_concat = 512

typedef __bf16 bf16x8 __attribute__((ext_vector_type(8)));
typedef float  f32x4  __attribute__((ext_vector_type(4)));

__device__ __forceinline__ unsigned short f2bf(float f) {
    union { float f; unsigned u; } v; v.f = f;
    unsigned r = v.u + 0x7FFF + ((v.u >> 16) & 1);   // RNE
    return (unsigned short)(r >> 16);
}

__device__ __forceinline__ void acc4(float4& a, const float4& v) {
    a.x += v.x; a.y += v.y; a.z += v.z; a.w += v.w;
}

// ---------------------------------------------------------------------------
// Merged prep: blocks [0,1140) build CSR rowptrs for both graphs (1 thread
// per edge); blocks [1140,1172) transpose+cast weights to Wt[n][k] bf16.
// ---------------------------------------------------------------------------
__global__ __launch_bounds__(256) void prep_kernel(
    const int* __restrict__ dst1, const int* __restrict__ dst2,
    const float* __restrict__ Ws, const float* __restrict__ Wn,
    int* __restrict__ rp1, int* __restrict__ rp2,
    unsigned short* __restrict__ Wt)     // [256, 512] bf16 bits
{
    __shared__ float t[64][65];
    if (blockIdx.x < 1140) {
        const int tid = blockIdx.x * 256 + threadIdx.x;
        if (tid < NE1) {
            const int d  = dst1[tid];
            const int dp = (tid == 0) ? -1 : dst1[tid - 1];
            for (int j = dp + 1; j <= d; ++j) rp1[j] = tid;
            if (tid == NE1 - 1) for (int j = d + 1; j <= NDST1; ++j) rp1[j] = NE1;
        } else {
            const int e  = tid - NE1;
            const int d  = dst2[e];
            const int dp = (e == 0) ? -1 : dst2[e - 1];
            for (int j = dp + 1; j <= d; ++j) rp2[j] = e;
            if (e == NE2 - 1) for (int j = d + 1; j <= NDST2; ++j) rp2[j] = NE2;
        }
        return;
    }
    const int tileid = blockIdx.x - 1140;       // 0..31
    const int kb = (tileid & 7) * 64, nb = (tileid >> 3) * 64;
    const float* __restrict__ W = (kb < 256) ? Ws : Wn;
    const int kofs = (kb < 256) ? kb : kb - 256;
    const int c  = threadIdx.x & 63;
    const int r0 = threadIdx.x >> 6;
    #pragma unroll
    for (int i = 0; i < 16; ++i) {
        const int r = r0 + i * 4;
        t[r][c] = W[(size_t)(kofs + r) * 256 + nb + c];
    }
    __syncthreads();
    #pragma unroll
    for (int i = 0; i < 16; ++i) {
        const int r = r0 + i * 4;
        Wt[(size_t)(nb + r) * 512 + kb + c] = f2bf(t[c][r]);
    }
}

// ---------------------------------------------------------------------------
// Layer-1 aggregation fused with bf16 A-matrix build.
// Abf[d][0:256] = bf16(x[d]); Abf[d][256:512] = bf16(mean_neigh(d)).
// One dst per wave, 4 waves/block. Edge loop unrolled x8 with independent
// accumulators -> 8 KB of row-gathers in flight per wave.
// ---------------------------------------------------------------------------
__global__ __launch_bounds__(256) void agg1_fused_kernel(
    const float* __restrict__ x,         // [NSRC1, 256]
    const int*   __restrict__ src_idx,   // [NE1]
    const int*   __restrict__ rowptr,    // [NDST1+1]
    unsigned short* __restrict__ Abf)    // [NDST1, 512] bf16 bits
{
    const int lane = threadIdx.x & 63;
    const int w    = threadIdx.x >> 6;
    const int d    = blockIdx.x * 4 + w;

    const int start = rowptr[d];
    const int end   = rowptr[d + 1];

    float4 a0 = make_float4(0.f,0.f,0.f,0.f);
    float4 a1 = a0, a2 = a0, a3 = a0, a4 = a0, a5 = a0, a6 = a0, a7 = a0;

    int e = start;
    for (; e + 8 <= end; e += 8) {
        const int s0 = src_idx[e + 0], s1 = src_idx[e + 1];
        const int s2 = src_idx[e + 2], s3 = src_idx[e + 3];
        const int s4 = src_idx[e + 4], s5 = src_idx[e + 5];
        const int s6 = src_idx[e + 6], s7 = src_idx[e + 7];
        const float4 v0 = ((const float4*)(x + (size_t)s0 * 256))[lane];
        const float4 v1 = ((const float4*)(x + (size_t)s1 * 256))[lane];
        const float4 v2 = ((const float4*)(x + (size_t)s2 * 256))[lane];
        const float4 v3 = ((const float4*)(x + (size_t)s3 * 256))[lane];
        const float4 v4 = ((const float4*)(x + (size_t)s4 * 256))[lane];
        const float4 v5 = ((const float4*)(x + (size_t)s5 * 256))[lane];
        const float4 v6 = ((const float4*)(x + (size_t)s6 * 256))[lane];
        const float4 v7 = ((const float4*)(x + (size_t)s7 * 256))[lane];
        acc4(a0, v0); acc4(a1, v1); acc4(a2, v2); acc4(a3, v3);
        acc4(a4, v4); acc4(a5, v5); acc4(a6, v6); acc4(a7, v7);
    }
    if (e + 4 <= end) {   // wave-uniform branch
        const int s0 = src_idx[e + 0], s1 = src_idx[e + 1];
        const int s2 = src_idx[e + 2], s3 = src_idx[e + 3];
        const float4 v0 = ((const float4*)(x + (size_t)s0 * 256))[lane];
        const float4 v1 = ((const float4*)(x + (size_t)s1 * 256))[lane];
        const float4 v2 = ((const float4*)(x + (size_t)s2 * 256))[lane];
        const float4 v3 = ((const float4*)(x + (size_t)s3 * 256))[lane];
        acc4(a0, v0); acc4(a1, v1); acc4(a2, v2); acc4(a3, v3);
        e += 4;
    }
    for (; e < end; ++e) {
        const int s = src_idx[e];
        const float4 v = ((const float4*)(x + (size_t)s * 256))[lane];
        acc4(a0, v);
    }
    acc4(a0, a1); acc4(a2, a3); acc4(a4, a5); acc4(a6, a7);
    acc4(a0, a2); acc4(a4, a6); acc4(a0, a4);

    const int deg = end - start;
    const float inv = 1.0f / (deg > 0 ? (float)deg : 1.0f);

    ushort4 nb;
    nb.x = f2bf(a0.x * inv); nb.y = f2bf(a0.y * inv);
    nb.z = f2bf(a0.z * inv); nb.w = f2bf(a0.w * inv);
    *(ushort4*)(Abf + (size_t)d * 512 + 256 + lane * 4) = nb;

    const float4 xv = ((const float4*)(x + (size_t)d * 256))[lane];
    ushort4 sf;
    sf.x = f2bf(xv.x); sf.y = f2bf(xv.y); sf.z = f2bf(xv.z); sf.w = f2bf(xv.w);
    *(ushort4*)(Abf + (size_t)d * 512 + lane * 4) = sf;
}

// ---------------------------------------------------------------------------
// Layer-1 GEMM on MFMA: h = relu(Abf @ Wt^T + b), fp32 out.
// M=11264, N=256, K=512. BM=128, BN=64, BK=32; 4 waves, each 64x32.
// ---------------------------------------------------------------------------
#define LDT 40   // LDS k-stride (bf16): 80B rows, 16B aligned, spreads banks

__global__ __launch_bounds__(256) void gemm1_mfma_kernel(
    const unsigned short* __restrict__ Abf,   // [NDST1, 512]
    const unsigned short* __restrict__ Wt,    // [256, 512]
    const float* __restrict__ bias,           // [256]
    float* __restrict__ h)                    // [NDST1, 256]
{
    __shared__ unsigned short As[128][LDT];
    __shared__ unsigned short Bs[64][LDT];

    const int tid  = threadIdx.x;
    const int lane = tid & 63;
    const int w    = tid >> 6;
    const int wm   = (w & 1) * 64;
    const int wn   = (w >> 1) * 32;
    const int mblk = blockIdx.x * 128;
    const int nblk = blockIdx.y * 64;

    const int r16 = lane & 15;
    const int k0  = (lane >> 4) * 8;

    f32x4 acc[4][2] = {};

    for (int kt = 0; kt < 512; kt += 32) {
        #pragma unroll
        for (int i = 0; i < 2; ++i) {
            const int idx = tid + i * 256;
            const int r  = idx >> 2;
            const int kk = (idx & 3) * 8;
            *(uint4*)&As[r][kk] =
                *(const uint4*)(Abf + (size_t)(mblk + r) * 512 + kt + kk);
        }
        {
            const int r  = tid >> 2;
            const int kk = (tid & 3) * 8;
            *(uint4*)&Bs[r][kk] =
                *(const uint4*)(Wt + (size_t)(nblk + r) * 512 + kt + kk);
        }
        __syncthreads();

        bf16x8 bfrag[2];
        #pragma unroll
        for (int ni = 0; ni < 2; ++ni)
            bfrag[ni] = *(const bf16x8*)&Bs[wn + ni * 16 + r16][k0];
        #pragma unroll
        for (int mi = 0; mi < 4; ++mi) {
            const bf16x8 afrag = *(const bf16x8*)&As[wm + mi * 16 + r16][k0];
            #pragma unroll
            for (int ni = 0; ni < 2; ++ni)
                acc[mi][ni] = __builtin_amdgcn_mfma_f32_16x16x32_bf16(
                    afrag, bfrag[ni], acc[mi][ni], 0, 0, 0);
        }
        __syncthreads();
    }

    #pragma unroll
    for (int mi = 0; mi < 4; ++mi) {
        #pragma unroll
        for (int ni = 0; ni < 2; ++ni) {
            const int col = nblk + wn + ni * 16 + r16;
            const float bb = bias[col];
            #pragma unroll
            for (int r = 0; r < 4; ++r) {
                const int row = mblk + wm + mi * 16 + (lane >> 4) * 4 + r;
                const float v = acc[mi][ni][r] + bb;
                h[(size_t)row * 256 + col] = v > 0.f ? v : 0.f;
            }
        }
    }
}

// ---------------------------------------------------------------------------
// Fused layer 2: per wave, aggregate neighbor mean of h into LDS, stage the
// self row, then out[m] = h[m] @ Ws2 + hn @ Wn2 + b2 (lane = out column).
// ---------------------------------------------------------------------------
__global__ __launch_bounds__(256) void layer2_kernel(
    const float* __restrict__ h,         // [NDST1, 256]
    const int*   __restrict__ src_idx,   // [NE2]
    const int*   __restrict__ rowptr,    // [NDST2+1]
    const float* __restrict__ Ws,        // [256, 47]
    const float* __restrict__ Wn,        // [256, 47]
    const float* __restrict__ b,         // [47]
    float* __restrict__ out)             // [NDST2, 47]
{
    __shared__ float hn[4][260];
    __shared__ float hs[4][260];

    const int lane = threadIdx.x & 63;
    const int w    = threadIdx.x >> 6;
    const int m    = blockIdx.x * 4 + w;

    const int start = rowptr[m];
    const int end   = rowptr[m + 1];

    float4 a0 = make_float4(0.f,0.f,0.f,0.f);
    float4 a1 = a0, a2 = a0, a3 = a0;
    int e = start;
    for (; e + 4 <= end; e += 4) {
        const int s0 = src_idx[e + 0], s1 = src_idx[e + 1];
        const int s2 = src_idx[e + 2], s3 = src_idx[e + 3];
        const float4 v0 = ((const float4*)(h + (size_t)s0 * 256))[lane];
        const float4 v1 = ((const float4*)(h + (size_t)s1 * 256))[lane];
        const float4 v2 = ((const float4*)(h + (size_t)s2 * 256))[lane];
        const float4 v3 = ((const float4*)(h + (size_t)s3 * 256))[lane];
        acc4(a0, v0); acc4(a1, v1); acc4(a2, v2); acc4(a3, v3);
    }
    for (; e < end; ++e) {
        const int s = src_idx[e];
        const float4 v = ((const float4*)(h + (size_t)s * 256))[lane];
        acc4(a0, v);
    }
    acc4(a0, a1); acc4(a2, a3); acc4(a0, a2);

    const int deg = end - start;
    const float inv = 1.0f / (deg > 0 ? (float)deg : 1.0f);
    a0.x *= inv; a0.y *= inv; a0.z *= inv; a0.w *= inv;
    *(float4*)&hn[w][lane * 4] = a0;

    const float4 sv = ((const float4*)(h + (size_t)m * 256))[lane];
    *(float4*)&hs[w][lane * 4] = sv;
    __syncthreads();

    if (lane < 47) {
        float acc = b[lane];
        #pragma unroll 4
        for (int k = 0; k < 256; ++k) {
            acc += hs[w][k] * Ws[k * 47 + lane] + hn[w][k] * Wn[k * 47 + lane];
        }
        out[(size_t)m * 47 + lane] = acc;
    }
}

extern "C" void kernel_launch(void* const* d_in, const int* in_sizes, int n_in,
                              void* d_out, int out_size, void* d_ws, size_t ws_size,
                              hipStream_t stream) {
    const float* x    = (const float*)d_in[0];
    const int*   src1 = (const int*)  d_in[1];
    const int*   dst1 = (const int*)  d_in[2];
    const int*   src2 = (const int*)  d_in[3];
    const int*   dst2 = (const int*)  d_in[4];
    const float* Ws1  = (const float*)d_in[5];
    const float* Wn1  = (const float*)d_in[6];
    const float* b1   = (const float*)d_in[7];
    const float* Ws2  = (const float*)d_in[8];
    const float* Wn2  = (const float*)d_in[9];
    const float* b2   = (const float*)d_in[10];
    float* out = (float*)d_out;

    char* ws = (char*)d_ws;
    const size_t sz_Abf = (size_t)NDST1 * 512 * sizeof(unsigned short); // 11.5 MB
    const size_t sz_h   = (size_t)NDST1 * 256 * sizeof(float);          // 11.5 MB
    const size_t sz_Wt  = (size_t)256 * 512 * sizeof(unsigned short);   // 256 KB
    const size_t sz_rp1 = (size_t)(NDST1 + 2) * sizeof(int);
    unsigned short* Abf = (unsigned short*)(ws);
    float*          h   = (float*)(ws + sz_Abf);
    unsigned short* Wt  = (unsigned short*)(ws + sz_Abf + sz_h);
    int*            rp1 = (int*)(ws + sz_Abf + sz_h + sz_Wt);
    int*            rp2 = (int*)(ws + sz_Abf + sz_h + sz_Wt + sz_rp1);

    // rowptr (both graphs) + weight transpose, one launch
    prep_kernel<<<1172, 256, 0, stream>>>(dst1, dst2, Ws1, Wn1, rp1, rp2, Wt);
    // Layer 1 aggregation fused with bf16 A build
    agg1_fused_kernel<<<NDST1 / 4, 256, 0, stream>>>(x, src1, rp1, Abf);
    // Layer 1 MFMA GEMM + bias + relu
    dim3 g1(NDST1 / 128, 256 / 64);
    gemm1_mfma_kernel<<<g1, 256, 0, stream>>>(Abf, Wt, b1, h);
    // Layer 2: aggregation + output GEMM fused
    layer2_kernel<<<NDST2 / 4, 256, 0, stream>>>(h, src2, rp2, Ws2, Wn2, b2, out);
}

// Round 5
// 445.444 us; speedup vs baseline: 1.1185x; 1.0106x over previous
//
#include <hip/hip_runtime.h>

#define NSRC1 292864
#define NDST1 11264
#define NE1   281600
#define NDST2 1024
#define NE2   10240
// IN = H = 256, C = 47, K_concat = 512

typedef __bf16 bf16x8 __attribute__((ext_vector_type(8)));
typedef float  f32x4  __attribute__((ext_vector_type(4)));

__device__ __forceinline__ unsigned short f2bf(float f) {
    union { float f; unsigned u; } v; v.f = f;
    unsigned r = v.u + 0x7FFF + ((v.u >> 16) & 1);   // RNE
    return (unsigned short)(r >> 16);
}

__device__ __forceinline__ void acc4(float4& a, const float4& v) {
    a.x += v.x; a.y += v.y; a.z += v.z; a.w += v.w;
}

// ---------------------------------------------------------------------------
// Merged prep: blocks [0,1140) build CSR rowptrs for both graphs (1 thread
// per edge); blocks [1140,1172) transpose+cast weights to Wt[n][k] bf16.
// ---------------------------------------------------------------------------
__global__ __launch_bounds__(256) void prep_kernel(
    const int* __restrict__ dst1, const int* __restrict__ dst2,
    const float* __restrict__ Ws, const float* __restrict__ Wn,
    int* __restrict__ rp1, int* __restrict__ rp2,
    unsigned short* __restrict__ Wt)     // [256, 512] bf16 bits
{
    __shared__ float t[64][65];
    if (blockIdx.x < 1140) {
        const int tid = blockIdx.x * 256 + threadIdx.x;
        if (tid < NE1) {
            const int d  = dst1[tid];
            const int dp = (tid == 0) ? -1 : dst1[tid - 1];
            for (int j = dp + 1; j <= d; ++j) rp1[j] = tid;
            if (tid == NE1 - 1) for (int j = d + 1; j <= NDST1; ++j) rp1[j] = NE1;
        } else {
            const int e  = tid - NE1;
            const int d  = dst2[e];
            const int dp = (e == 0) ? -1 : dst2[e - 1];
            for (int j = dp + 1; j <= d; ++j) rp2[j] = e;
            if (e == NE2 - 1) for (int j = d + 1; j <= NDST2; ++j) rp2[j] = NE2;
        }
        return;
    }
    const int tileid = blockIdx.x - 1140;       // 0..31
    const int kb = (tileid & 7) * 64, nb = (tileid >> 3) * 64;
    const float* __restrict__ W = (kb < 256) ? Ws : Wn;
    const int kofs = (kb < 256) ? kb : kb - 256;
    const int c  = threadIdx.x & 63;
    const int r0 = threadIdx.x >> 6;
    #pragma unroll
    for (int i = 0; i < 16; ++i) {
        const int r = r0 + i * 4;
        t[r][c] = W[(size_t)(kofs + r) * 256 + nb + c];
    }
    __syncthreads();
    #pragma unroll
    for (int i = 0; i < 16; ++i) {
        const int r = r0 + i * 4;
        Wt[(size_t)(nb + r) * 512 + kb + c] = f2bf(t[c][r]);
    }
}

// ---------------------------------------------------------------------------
// Layer-1 aggregation fused with bf16 A-matrix build.
// Abf[d][0:256] = bf16(x[d]); Abf[d][256:512] = bf16(mean_neigh(d)).
// One dst per wave, 4 waves/block. Edge loop unrolled x8 with independent
// accumulators. Indices fetched via wave-uniform (scalar) loads so the
// vmem queue carries only row gathers.
// ---------------------------------------------------------------------------
__global__ __launch_bounds__(256) void agg1_fused_kernel(
    const float* __restrict__ x,         // [NSRC1, 256]
    const int*   __restrict__ src_idx,   // [NE1]
    const int*   __restrict__ rowptr,    // [NDST1+1]
    unsigned short* __restrict__ Abf)    // [NDST1, 512] bf16 bits
{
    const int lane = threadIdx.x & 63;
    const int w    = threadIdx.x >> 6;
    const int d    = blockIdx.x * 4 + w;

    const int start = rowptr[d];
    const int end   = rowptr[d + 1];

    const float4* __restrict__ xcol = (const float4*)x + lane;  // row r -> xcol[r*64]

    float4 a0 = make_float4(0.f,0.f,0.f,0.f);
    float4 a1 = a0, a2 = a0, a3 = a0, a4 = a0, a5 = a0, a6 = a0, a7 = a0;

    int e = start;
    for (; e + 8 <= end; e += 8) {
        const int eu = __builtin_amdgcn_readfirstlane(e);   // provably uniform -> s_load
        const int s0 = src_idx[eu + 0], s1 = src_idx[eu + 1];
        const int s2 = src_idx[eu + 2], s3 = src_idx[eu + 3];
        const int s4 = src_idx[eu + 4], s5 = src_idx[eu + 5];
        const int s6 = src_idx[eu + 6], s7 = src_idx[eu + 7];
        const float4 v0 = xcol[(size_t)s0 * 64];
        const float4 v1 = xcol[(size_t)s1 * 64];
        const float4 v2 = xcol[(size_t)s2 * 64];
        const float4 v3 = xcol[(size_t)s3 * 64];
        const float4 v4 = xcol[(size_t)s4 * 64];
        const float4 v5 = xcol[(size_t)s5 * 64];
        const float4 v6 = xcol[(size_t)s6 * 64];
        const float4 v7 = xcol[(size_t)s7 * 64];
        acc4(a0, v0); acc4(a1, v1); acc4(a2, v2); acc4(a3, v3);
        acc4(a4, v4); acc4(a5, v5); acc4(a6, v6); acc4(a7, v7);
    }
    if (e + 4 <= end) {   // wave-uniform branch
        const int eu = __builtin_amdgcn_readfirstlane(e);
        const int s0 = src_idx[eu + 0], s1 = src_idx[eu + 1];
        const int s2 = src_idx[eu + 2], s3 = src_idx[eu + 3];
        const float4 v0 = xcol[(size_t)s0 * 64];
        const float4 v1 = xcol[(size_t)s1 * 64];
        const float4 v2 = xcol[(size_t)s2 * 64];
        const float4 v3 = xcol[(size_t)s3 * 64];
        acc4(a0, v0); acc4(a1, v1); acc4(a2, v2); acc4(a3, v3);
        e += 4;
    }
    for (; e < end; ++e) {
        const int eu = __builtin_amdgcn_readfirstlane(e);
        const int s = src_idx[eu];
        acc4(a0, xcol[(size_t)s * 64]);
    }
    acc4(a0, a1); acc4(a2, a3); acc4(a4, a5); acc4(a6, a7);
    acc4(a0, a2); acc4(a4, a6); acc4(a0, a4);

    const int deg = end - start;
    const float inv = 1.0f / (deg > 0 ? (float)deg : 1.0f);

    ushort4 nb;
    nb.x = f2bf(a0.x * inv); nb.y = f2bf(a0.y * inv);
    nb.z = f2bf(a0.z * inv); nb.w = f2bf(a0.w * inv);
    *(ushort4*)(Abf + (size_t)d * 512 + 256 + lane * 4) = nb;

    const float4 xv = xcol[(size_t)d * 64];
    ushort4 sf;
    sf.x = f2bf(xv.x); sf.y = f2bf(xv.y); sf.z = f2bf(xv.z); sf.w = f2bf(xv.w);
    *(ushort4*)(Abf + (size_t)d * 512 + lane * 4) = sf;
}

// ---------------------------------------------------------------------------
// Layer-1 GEMM on MFMA: h = relu(Abf @ Wt^T + b), fp32 out.
// M=11264, N=256, K=512. BM=128, BN=64, BK=32; 4 waves, each 64x32.
// ---------------------------------------------------------------------------
#define LDT 40   // LDS k-stride (bf16): 80B rows, 16B aligned, spreads banks

__global__ __launch_bounds__(256) void gemm1_mfma_kernel(
    const unsigned short* __restrict__ Abf,   // [NDST1, 512]
    const unsigned short* __restrict__ Wt,    // [256, 512]
    const float* __restrict__ bias,           // [256]
    float* __restrict__ h)                    // [NDST1, 256]
{
    __shared__ unsigned short As[128][LDT];
    __shared__ unsigned short Bs[64][LDT];

    const int tid  = threadIdx.x;
    const int lane = tid & 63;
    const int w    = tid >> 6;
    const int wm   = (w & 1) * 64;
    const int wn   = (w >> 1) * 32;
    const int mblk = blockIdx.x * 128;
    const int nblk = blockIdx.y * 64;

    const int r16 = lane & 15;
    const int k0  = (lane >> 4) * 8;

    f32x4 acc[4][2] = {};

    for (int kt = 0; kt < 512; kt += 32) {
        #pragma unroll
        for (int i = 0; i < 2; ++i) {
            const int idx = tid + i * 256;
            const int r  = idx >> 2;
            const int kk = (idx & 3) * 8;
            *(uint4*)&As[r][kk] =
                *(const uint4*)(Abf + (size_t)(mblk + r) * 512 + kt + kk);
        }
        {
            const int r  = tid >> 2;
            const int kk = (tid & 3) * 8;
            *(uint4*)&Bs[r][kk] =
                *(const uint4*)(Wt + (size_t)(nblk + r) * 512 + kt + kk);
        }
        __syncthreads();

        bf16x8 bfrag[2];
        #pragma unroll
        for (int ni = 0; ni < 2; ++ni)
            bfrag[ni] = *(const bf16x8*)&Bs[wn + ni * 16 + r16][k0];
        #pragma unroll
        for (int mi = 0; mi < 4; ++mi) {
            const bf16x8 afrag = *(const bf16x8*)&As[wm + mi * 16 + r16][k0];
            #pragma unroll
            for (int ni = 0; ni < 2; ++ni)
                acc[mi][ni] = __builtin_amdgcn_mfma_f32_16x16x32_bf16(
                    afrag, bfrag[ni], acc[mi][ni], 0, 0, 0);
        }
        __syncthreads();
    }

    #pragma unroll
    for (int mi = 0; mi < 4; ++mi) {
        #pragma unroll
        for (int ni = 0; ni < 2; ++ni) {
            const int col = nblk + wn + ni * 16 + r16;
            const float bb = bias[col];
            #pragma unroll
            for (int r = 0; r < 4; ++r) {
                const int row = mblk + wm + mi * 16 + (lane >> 4) * 4 + r;
                const float v = acc[mi][ni][r] + bb;
                h[(size_t)row * 256 + col] = v > 0.f ? v : 0.f;
            }
        }
    }
}

// ---------------------------------------------------------------------------
// Fused layer 2: per wave, aggregate neighbor mean of h into LDS, stage the
// self row, then out[m] = h[m] @ Ws2 + hn @ Wn2 + b2 (lane = out column).
// ---------------------------------------------------------------------------
__global__ __launch_bounds__(256) void layer2_kernel(
    const float* __restrict__ h,         // [NDST1, 256]
    const int*   __restrict__ src_idx,   // [NE2]
    const int*   __restrict__ rowptr,    // [NDST2+1]
    const float* __restrict__ Ws,        // [256, 47]
    const float* __restrict__ Wn,        // [256, 47]
    const float* __restrict__ b,         // [47]
    float* __restrict__ out)             // [NDST2, 47]
{
    __shared__ float hn[4][260];
    __shared__ float hs[4][260];

    const int lane = threadIdx.x & 63;
    const int w    = threadIdx.x >> 6;
    const int m    = blockIdx.x * 4 + w;

    const int start = rowptr[m];
    const int end   = rowptr[m + 1];

    const float4* __restrict__ hcol = (const float4*)h + lane;

    float4 a0 = make_float4(0.f,0.f,0.f,0.f);
    float4 a1 = a0, a2 = a0, a3 = a0;
    int e = start;
    for (; e + 4 <= end; e += 4) {
        const int eu = __builtin_amdgcn_readfirstlane(e);
        const int s0 = src_idx[eu + 0], s1 = src_idx[eu + 1];
        const int s2 = src_idx[eu + 2], s3 = src_idx[eu + 3];
        const float4 v0 = hcol[(size_t)s0 * 64];
        const float4 v1 = hcol[(size_t)s1 * 64];
        const float4 v2 = hcol[(size_t)s2 * 64];
        const float4 v3 = hcol[(size_t)s3 * 64];
        acc4(a0, v0); acc4(a1, v1); acc4(a2, v2); acc4(a3, v3);
    }
    for (; e < end; ++e) {
        const int eu = __builtin_amdgcn_readfirstlane(e);
        const int s = src_idx[eu];
        acc4(a0, hcol[(size_t)s * 64]);
    }
    acc4(a0, a1); acc4(a2, a3); acc4(a0, a2);

    const int deg = end - start;
    const float inv = 1.0f / (deg > 0 ? (float)deg : 1.0f);
    a0.x *= inv; a0.y *= inv; a0.z *= inv; a0.w *= inv;
    *(float4*)&hn[w][lane * 4] = a0;

    const float4 sv = hcol[(size_t)m * 64];
    *(float4*)&hs[w][lane * 4] = sv;
    __syncthreads();

    if (lane < 47) {
        float acc = b[lane];
        #pragma unroll 4
        for (int k = 0; k < 256; ++k) {
            acc += hs[w][k] * Ws[k * 47 + lane] + hn[w][k] * Wn[k * 47 + lane];
        }
        out[(size_t)m * 47 + lane] = acc;
    }
}

extern "C" void kernel_launch(void* const* d_in, const int* in_sizes, int n_in,
                              void* d_out, int out_size, void* d_ws, size_t ws_size,
                              hipStream_t stream) {
    const float* x    = (const float*)d_in[0];
    const int*   src1 = (const int*)  d_in[1];
    const int*   dst1 = (const int*)  d_in[2];
    const int*   src2 = (const int*)  d_in[3];
    const int*   dst2 = (const int*)  d_in[4];
    const float* Ws1  = (const float*)d_in[5];
    const float* Wn1  = (const float*)d_in[6];
    const float* b1   = (const float*)d_in[7];
    const float* Ws2  = (const float*)d_in[8];
    const float* Wn2  = (const float*)d_in[9];
    const float* b2   = (const float*)d_in[10];
    float* out = (float*)d_out;

    char* ws = (char*)d_ws;
    const size_t sz_Abf = (size_t)NDST1 * 512 * sizeof(unsigned short); // 11.5 MB
    const size_t sz_h   = (size_t)NDST1 * 256 * sizeof(float);          // 11.5 MB
    const size_t sz_Wt  = (size_t)256 * 512 * sizeof(unsigned short);   // 256 KB
    const size_t sz_rp1 = (size_t)(NDST1 + 2) * sizeof(int);
    unsigned short* Abf = (unsigned short*)(ws);
    float*          h   = (float*)(ws + sz_Abf);
    unsigned short* Wt  = (unsigned short*)(ws + sz_Abf + sz_h);
    int*            rp1 = (int*)(ws + sz_Abf + sz_h + sz_Wt);
    int*            rp2 = (int*)(ws + sz_Abf + sz_h + sz_Wt + sz_rp1);

    // rowptr (both graphs) + weight transpose, one launch
    prep_kernel<<<1172, 256, 0, stream>>>(dst1, dst2, Ws1, Wn1, rp1, rp2, Wt);
    // Layer 1 aggregation fused with bf16 A build
    agg1_fused_kernel<<<NDST1 / 4, 256, 0, stream>>>(x, src1, rp1, Abf);
    // Layer 1 MFMA GEMM + bias + relu
    dim3 g1(NDST1 / 128, 256 / 64);
    gemm1_mfma_kernel<<<g1, 256, 0, stream>>>(Abf, Wt, b1, h);
    // Layer 2: aggregation + output GEMM fused
    layer2_kernel<<<NDST2 / 4, 256, 0, stream>>>(h, src2, rp2, Ws2, Wn2, b2, out);
}